// Round 3
// baseline (918.809 us; speedup 1.0000x reference)
//
#include <hip/hip_runtime.h>
#include <math.h>

#define N_NODES 100000
#define C_CH    64
#define E_EDGES 1200000
#define KD      32
#define HID     256
#define NPG     32
#define NGROUPS (N_NODES / NPG)   // 3125 exact

typedef short bf16x8 __attribute__((ext_vector_type(8)));
typedef float f32x4  __attribute__((ext_vector_type(4)));

__device__ __forceinline__ short f2bf(float f) {
    unsigned u = __builtin_bit_cast(unsigned, f);
    u = (u + 0x7fffu + ((u >> 16) & 1u)) >> 16;   // RNE
    return (short)u;
}

// ---------------------------------------------------------------------------
// CSR build: histogram -> single-block scan -> fill (eids in dst order)
// ---------------------------------------------------------------------------
__global__ __launch_bounds__(256) void hist_kernel(const int* __restrict__ ei,
                                                   int* __restrict__ deg) {
    int i = blockIdx.x * 256 + threadIdx.x;
    int stride = gridDim.x * 256;
    for (int e = i; e < E_EDGES; e += stride) {
        int dst = ei[E_EDGES + e];
        if ((unsigned)dst < (unsigned)N_NODES) atomicAdd(&deg[dst], 1);
    }
}

// deg_pos: in = degree histogram, out = exclusive prefix (fill cursor)
__global__ __launch_bounds__(1024) void scan_kernel(int* __restrict__ deg_pos,
                                                    int* __restrict__ off) {
    __shared__ int s[1024];
    const int t = threadIdx.x;
    const int CHUNK = (N_NODES + 1023) / 1024;   // 98
    const int base = t * CHUNK;
    const int end  = min(base + CHUNK, N_NODES);
    int sum = 0;
    for (int i = base; i < end; ++i) sum += deg_pos[i];
    s[t] = sum;
    __syncthreads();
    for (int d = 1; d < 1024; d <<= 1) {
        int v = (t >= d) ? s[t - d] : 0;
        __syncthreads();
        s[t] += v;
        __syncthreads();
    }
    int run = s[t] - sum;                        // exclusive prefix
    for (int i = base; i < end; ++i) {
        int dv = deg_pos[i];                     // read BEFORE overwrite
        off[i] = run;
        deg_pos[i] = run;                        // pos cursor
        run += dv;
    }
    if (t == 1023) off[N_NODES] = s[1023];
}

__global__ __launch_bounds__(256) void fill_kernel(const int* __restrict__ ei,
                                                   int* __restrict__ pos,
                                                   int* __restrict__ eids) {
    int i = blockIdx.x * 256 + threadIdx.x;
    int stride = gridDim.x * 256;
    for (int e = i; e < E_EDGES; e += stride) {
        int dst = ei[E_EDGES + e];
        if ((unsigned)dst < (unsigned)N_NODES) {
            int p = atomicAdd(&pos[dst], 1);
            eids[p] = e;
        }
    }
}

// ---------------------------------------------------------------------------
// Gather: one wave per dst node; lane = channel. Edge ids wave-uniform ->
// eids/ei/kb rows all scalar (s_load); register accumulation; x1 written once.
// No float atomics anywhere.
// ---------------------------------------------------------------------------
__global__ __launch_bounds__(256) void gather_kernel(
    const float* __restrict__ x,  const float* __restrict__ kb,
    const int*   __restrict__ ei, const float* __restrict__ kW,
    const int*   __restrict__ off, const int* __restrict__ eids,
    float*       __restrict__ x1)
{
    const int lane = threadIdx.x & 63;
    const int wid  = blockIdx.x * 4 + (threadIdx.x >> 6);
    const int nw   = gridDim.x * 4;

    float wcol[KD];
    #pragma unroll
    for (int k = 0; k < KD; ++k) wcol[k] = kW[lane * KD + k];

    for (int n0 = wid; n0 < N_NODES; n0 += nw) {
        const int n   = __builtin_amdgcn_readfirstlane(n0);
        const int beg = off[n];
        const int end = off[n + 1];
        float acc = 0.f;
        for (int i = beg; i < end; ++i) {
            const int eid = eids[i];                 // uniform -> s_load
            const int src = ei[eid];                 // s_load
            const float* __restrict__ kbr = kb + (size_t)eid * KD;
            float kc = 0.f;
            #pragma unroll
            for (int k = 0; k < KD; ++k) kc += kbr[k] * wcol[k];
            acc += x[(size_t)src * C_CH + lane] * kc;
        }
        x1[(size_t)n * C_CH + lane] = acc;
    }
}

// ---------------------------------------------------------------------------
// Node: conv_bias + LN (fp32) -> bf16 MFMA GEMM1 -> exact GELU -> bf16 MFMA
// GEMM2 -> layerscale + residual. 32 nodes / group / block. Weight fragments
// live in registers (loaded once). bf16 MLP error is damped by layer_scale
// (1e-6) so output error ~1e-7.
// mfma_f32_16x16x32_bf16 layouts (HW-verified):
//   A: lane holds A[m=lane&15][k=(lane>>4)*8 + j], j=0..7
//   B: lane holds B[k=(lane>>4)*8 + j][n=lane&15]
//   C/D: col=lane&15, row=(lane>>4)*4 + reg
// ---------------------------------------------------------------------------
__global__ __launch_bounds__(256, 2) void node_kernel(
    const float* __restrict__ x,  const float* __restrict__ x1,
    const float* __restrict__ conv_bias, const float* __restrict__ gamma,
    const float* __restrict__ beta, const float* __restrict__ W1,
    const float* __restrict__ b1, const float* __restrict__ W2,
    const float* __restrict__ b2, const float* __restrict__ ls,
    float* __restrict__ out)
{
    __shared__ short lnb[NPG][C_CH + 8];   // bf16 LN out, row 144B (16B-mult)
    __shared__ short gb[NPG][HID + 8];     // bf16 GELU out, row 528B (16B-mult)

    const int t    = threadIdx.x;
    const int lane = t & 63;
    const int w    = t >> 6;
    const int nlo  = lane & 15;
    const int quad = lane >> 4;

    // ---- weight fragments in registers (loaded once per block) ----
    // GEMM1: B1[i][j] = W1[j][i]; wave w owns j-tiles 4w..4w+3
    bf16x8 b1f[4][2];
    float  b1v[4];
    #pragma unroll
    for (int t1 = 0; t1 < 4; ++t1) {
        const int j = (4 * w + t1) * 16 + nlo;
        b1v[t1] = b1[j];
        #pragma unroll
        for (int s = 0; s < 2; ++s) {
            const float* p = W1 + (size_t)j * C_CH + s * 32 + quad * 8;
            #pragma unroll
            for (int q = 0; q < 8; ++q) b1f[t1][s][q] = f2bf(p[q]);
        }
    }
    // GEMM2: B2[j][c] = W2[c][j]; wave w owns c-tile w
    bf16x8 b2f[8];
    #pragma unroll
    for (int s2 = 0; s2 < 8; ++s2) {
        const float* p = W2 + (size_t)(w * 16 + nlo) * HID + s2 * 32 + quad * 8;
        #pragma unroll
        for (int q = 0; q < 8; ++q) b2f[s2][q] = f2bf(p[q]);
    }
    const float biasc  = conv_bias[lane];
    const float gammac = gamma[lane];
    const float betac  = beta[lane];
    const float b2v    = b2[w * 16 + nlo];
    const float lsv    = ls[w * 16 + nlo];

    for (int g = blockIdx.x; g < NGROUPS; g += gridDim.x) {
        const int base = g * NPG;

        // ---- phase 1: bias + LN (fp32), wave w -> nodes 8w..8w+7 ----
        #pragma unroll
        for (int q = 0; q < 8; ++q) {
            const int loc = w * 8 + q;
            float v = x1[(size_t)(base + loc) * C_CH + lane] + biasc;
            float s = v, ss = v * v;
            #pragma unroll
            for (int o = 32; o > 0; o >>= 1) {
                s  += __shfl_xor(s,  o, 64);
                ss += __shfl_xor(ss, o, 64);
            }
            float mu   = s * (1.f / 64.f);
            float rstd = rsqrtf(ss * (1.f / 64.f) - mu * mu + 1e-5f);
            lnb[loc][lane] = f2bf((v - mu) * rstd * gammac + betac);
        }
        __syncthreads();

        // ---- phase 2: GEMM1 (h1 = LN @ W1^T) + bias + exact GELU ----
        #pragma unroll
        for (int mt = 0; mt < 2; ++mt) {
            bf16x8 a1[2];
            #pragma unroll
            for (int s = 0; s < 2; ++s)
                a1[s] = *(const bf16x8*)&lnb[mt * 16 + nlo][s * 32 + quad * 8];
            #pragma unroll
            for (int t1 = 0; t1 < 4; ++t1) {
                f32x4 c = {0.f, 0.f, 0.f, 0.f};
                c = __builtin_amdgcn_mfma_f32_16x16x32_bf16(a1[0], b1f[t1][0], c, 0, 0, 0);
                c = __builtin_amdgcn_mfma_f32_16x16x32_bf16(a1[1], b1f[t1][1], c, 0, 0, 0);
                #pragma unroll
                for (int r = 0; r < 4; ++r) {
                    float h = c[r] + b1v[t1];
                    h = 0.5f * h * (1.f + erff(h * 0.70710678f));
                    gb[mt * 16 + quad * 4 + r][(4 * w + t1) * 16 + nlo] = f2bf(h);
                }
            }
        }
        __syncthreads();

        // ---- phase 3: GEMM2 (h2 = g @ W2^T) + bias + layerscale + residual ----
        #pragma unroll
        for (int mt = 0; mt < 2; ++mt) {
            f32x4 c2 = {0.f, 0.f, 0.f, 0.f};
            #pragma unroll
            for (int s2 = 0; s2 < 8; ++s2) {
                bf16x8 a2 = *(const bf16x8*)&gb[mt * 16 + nlo][s2 * 32 + quad * 8];
                c2 = __builtin_amdgcn_mfma_f32_16x16x32_bf16(a2, b2f[s2], c2, 0, 0, 0);
            }
            #pragma unroll
            for (int r = 0; r < 4; ++r) {
                const int node = base + mt * 16 + quad * 4 + r;
                const int cch  = w * 16 + nlo;
                float h2 = c2[r] + b2v;
                out[(size_t)node * C_CH + cch] =
                    lsv * h2 + x[(size_t)node * C_CH + cch];
            }
        }
        __syncthreads();  // gb reused next group by phase 2 writes after B1;
                          // keep one barrier to protect vs fast next-phase1+B1
    }
}

extern "C" void kernel_launch(void* const* d_in, const int* in_sizes, int n_in,
                              void* d_out, int out_size, void* d_ws, size_t ws_size,
                              hipStream_t stream) {
    const float* x   = (const float*)d_in[0];
    const float* kb  = (const float*)d_in[1];
    // d_in[2] = fiber_kernel_basis (unused)
    const int*   ei  = (const int*)d_in[3];
    const float* kW  = (const float*)d_in[4];
    const float* cb  = (const float*)d_in[5];
    const float* gm  = (const float*)d_in[6];
    const float* bt  = (const float*)d_in[7];
    const float* W1  = (const float*)d_in[8];
    const float* b1  = (const float*)d_in[9];
    const float* W2  = (const float*)d_in[10];
    const float* b2  = (const float*)d_in[11];
    const float* ls  = (const float*)d_in[12];
    float* out = (float*)d_out;

    // workspace layout (31.2 MB total)
    char* ws = (char*)d_ws;
    float* x1   = (float*)ws;                        // 25,600,000 B
    int*   off  = (int*)(ws + 25600000);             //    400,004 B (pad ->400,016)
    int*   pos  = (int*)(ws + 26000016);             //    400,000 B  (hist, then cursor)
    int*   eids = (int*)(ws + 26400016);             //  4,800,000 B

    hipMemsetAsync(pos, 0, N_NODES * sizeof(int), stream);
    hist_kernel<<<1024, 256, 0, stream>>>(ei, pos);
    scan_kernel<<<1, 1024, 0, stream>>>(pos, off);
    fill_kernel<<<1024, 256, 0, stream>>>(ei, pos, eids);
    gather_kernel<<<4096, 256, 0, stream>>>(x, kb, ei, kW, off, eids, x1);
    node_kernel<<<1024, 256, 0, stream>>>(x, x1, cb, gm, bt, W1, b1, W2, b2, ls, out);
}

// Round 4
// 403.720 us; speedup vs baseline: 2.2759x; 2.2759x over previous
//
#include <hip/hip_runtime.h>
#include <math.h>

#define N_NODES 100000
#define C_CH    64
#define E_EDGES 1200000
#define KD      32
#define HID     256
#define NPG     32
#define NGROUPS (N_NODES / NPG)     // 3125 exact
#define NCHUNK  (E_EDGES / 64)      // 18750 exact

typedef unsigned short ushort_t;
typedef short bf16x8 __attribute__((ext_vector_type(8)));
typedef short s2v    __attribute__((ext_vector_type(2)));
typedef float f32x4  __attribute__((ext_vector_type(4)));

__device__ __forceinline__ short f2bf(float f) {
    unsigned u = __builtin_bit_cast(unsigned, f);
    u = (u + 0x7fffu + ((u >> 16) & 1u)) >> 16;   // RNE
    return (short)u;
}
__device__ __forceinline__ float bf2f(ushort_t u) {
    return __builtin_bit_cast(float, (unsigned)u << 16);
}
__device__ __forceinline__ float bf2f_lo(unsigned p) {
    return __builtin_bit_cast(float, p << 16);
}
__device__ __forceinline__ float bf2f_hi(unsigned p) {
    return __builtin_bit_cast(float, p & 0xffff0000u);
}

// packed bf16x2 atomic add (HW global_atomic_pk_add_bf16 on gfx950)
__device__ __forceinline__ void pk_atomic_bf16(void* p, float m0, float m1) {
    s2v v; v[0] = f2bf(m0); v[1] = f2bf(m1);
#if __has_builtin(__builtin_amdgcn_global_atomic_fadd_v2bf16)
    typedef __attribute__((address_space(1))) s2v* gpt;
    __builtin_amdgcn_global_atomic_fadd_v2bf16((gpt)(unsigned long long)p, v);
#else
    unsigned* up = (unsigned*)p;
    unsigned old = __hip_atomic_load(up, __ATOMIC_RELAXED, __HIP_MEMORY_SCOPE_AGENT);
    unsigned assumed;
    do {
        assumed = old;
        float a0 = bf2f_lo(assumed) + m0;
        float a1 = bf2f_hi(assumed) + m1;
        unsigned nv = (unsigned)(ushort_t)f2bf(a0)
                    | ((unsigned)(ushort_t)f2bf(a1) << 16);
        old = atomicCAS(up, assumed, nv);
    } while (old != assumed);
#endif
}

// ---------------------------------------------------------------------------
// K1: fused depthwise-conv message passing, no CSR, no fp32 atomics.
// Block = 4 waves; block processes 64 edges per chunk (16 per wave).
// Per 16-edge tile:
//   coef[m][ch] = kb[e0+m] . kW[ch]  via 4x mfma_16x16x32_bf16
//     A: lane holds kb[(e0 + lane&15)][quad*8+j]  (coalesced streaming reads)
//     B[t]: lane holds kW[16t + lane&15][quad*8+j] (preloaded, 16 VGPRs)
//     D: lane holds coef[quad*4+r][16t + lane&15]
//   coef -> per-wave LDS (stride 34 dwords: banks = 8*quad+2*r+oct, conflict-free)
//   scatter: 8 iters; lanes 0-31 edge j, lanes 32-63 edge j+8; each lane does
//   one channel PAIR: ds_read dword coef pair + float2 x load + pk bf16 atomic.
// All edge-index loads are wave-uniform -> s_load; all heavy traffic is
// vector/streaming (throughput context, no dependent scalar chains).
// ---------------------------------------------------------------------------
__global__ __launch_bounds__(256) void edge_kernel(
    const float* __restrict__ x, const float* __restrict__ kb,
    const int* __restrict__ ei, const float* __restrict__ kW,
    ushort_t* __restrict__ x1b)
{
    __shared__ int cbuf[4][16][34];   // 8.7 KB: [wave][edge-row][dword]

    const int t    = threadIdx.x;
    const int lane = t & 63;
    const int w    = __builtin_amdgcn_readfirstlane(t >> 6);
    const int nlo  = lane & 15;
    const int quad = lane >> 4;
    const int cp   = lane & 31;       // channel-pair index
    const int hf   = lane >> 5;       // half-wave: edge j vs j+8

    // B fragments: B[k][n] = kW[16t+n][k], lane k = quad*8+j
    bf16x8 bW[4];
    #pragma unroll
    for (int tt = 0; tt < 4; ++tt) {
        const float* p = kW + (size_t)(16 * tt + nlo) * KD + quad * 8;
        #pragma unroll
        for (int q = 0; q < 8; ++q) bW[tt][q] = f2bf(p[q]);
    }

    short* srow = (short*)&cbuf[w][0][0];   // row stride 68 shorts

    for (int c = blockIdx.x; c < NCHUNK; c += gridDim.x) {
        const int e0 = c * 64 + w * 16;

        // ---- MFMA coef for edges e0..e0+15 ----
        const float* ap = kb + (size_t)(e0 + nlo) * KD + quad * 8;
        bf16x8 af;
        #pragma unroll
        for (int q = 0; q < 8; ++q) af[q] = f2bf(ap[q]);
        #pragma unroll
        for (int tt = 0; tt < 4; ++tt) {
            f32x4 d = {0.f, 0.f, 0.f, 0.f};
            d = __builtin_amdgcn_mfma_f32_16x16x32_bf16(af, bW[tt], d, 0, 0, 0);
            #pragma unroll
            for (int r = 0; r < 4; ++r)
                srow[(quad * 4 + r) * 68 + 16 * tt + nlo] = f2bf(d[r]);
        }
        __syncthreads();

        // ---- scatter: 2 edges per instruction slot, full 64-lane use ----
        #pragma unroll
        for (int j = 0; j < 8; ++j) {
            const int sA = ei[e0 + j],           sB = ei[e0 + j + 8];
            const int dA = ei[E_EDGES + e0 + j], dB = ei[E_EDGES + e0 + j + 8];
            const int src = hf ? sB : sA;
            const int dst = hf ? dB : dA;
            const unsigned cf = (unsigned)cbuf[w][j + hf * 8][cp];
            const float2 x2 = *(const float2*)(x + (size_t)src * C_CH + 2 * cp);
            pk_atomic_bf16(x1b + (size_t)dst * C_CH + 2 * cp,
                           x2.x * bf2f_lo(cf), x2.y * bf2f_hi(cf));
        }
        __syncthreads();
    }
}

// ---------------------------------------------------------------------------
// K2: conv_bias + LN (fp32) -> bf16 MFMA GEMM1 -> exact GELU -> bf16 MFMA
// GEMM2 -> layerscale + residual. x1 now bf16. (Structure verified in R3.)
// ---------------------------------------------------------------------------
__global__ __launch_bounds__(256, 2) void node_kernel(
    const float* __restrict__ x,  const ushort_t* __restrict__ x1b,
    const float* __restrict__ conv_bias, const float* __restrict__ gamma,
    const float* __restrict__ beta, const float* __restrict__ W1,
    const float* __restrict__ b1, const float* __restrict__ W2,
    const float* __restrict__ b2, const float* __restrict__ ls,
    float* __restrict__ out)
{
    __shared__ short lnb[NPG][C_CH + 8];
    __shared__ short gb[NPG][HID + 8];

    const int t    = threadIdx.x;
    const int lane = t & 63;
    const int w    = t >> 6;
    const int nlo  = lane & 15;
    const int quad = lane >> 4;

    bf16x8 b1f[4][2];
    float  b1v[4];
    #pragma unroll
    for (int t1 = 0; t1 < 4; ++t1) {
        const int j = (4 * w + t1) * 16 + nlo;
        b1v[t1] = b1[j];
        #pragma unroll
        for (int s = 0; s < 2; ++s) {
            const float* p = W1 + (size_t)j * C_CH + s * 32 + quad * 8;
            #pragma unroll
            for (int q = 0; q < 8; ++q) b1f[t1][s][q] = f2bf(p[q]);
        }
    }
    bf16x8 b2f[8];
    #pragma unroll
    for (int s2 = 0; s2 < 8; ++s2) {
        const float* p = W2 + (size_t)(w * 16 + nlo) * HID + s2 * 32 + quad * 8;
        #pragma unroll
        for (int q = 0; q < 8; ++q) b2f[s2][q] = f2bf(p[q]);
    }
    const float biasc  = conv_bias[lane];
    const float gammac = gamma[lane];
    const float betac  = beta[lane];
    const float b2v    = b2[w * 16 + nlo];
    const float lsv    = ls[w * 16 + nlo];

    for (int g = blockIdx.x; g < NGROUPS; g += gridDim.x) {
        const int base = g * NPG;

        #pragma unroll
        for (int q = 0; q < 8; ++q) {
            const int loc = w * 8 + q;
            float v = bf2f(x1b[(size_t)(base + loc) * C_CH + lane]) + biasc;
            float s = v, ss = v * v;
            #pragma unroll
            for (int o = 32; o > 0; o >>= 1) {
                s  += __shfl_xor(s,  o, 64);
                ss += __shfl_xor(ss, o, 64);
            }
            float mu   = s * (1.f / 64.f);
            float rstd = rsqrtf(ss * (1.f / 64.f) - mu * mu + 1e-5f);
            lnb[loc][lane] = f2bf((v - mu) * rstd * gammac + betac);
        }
        __syncthreads();

        #pragma unroll
        for (int mt = 0; mt < 2; ++mt) {
            bf16x8 a1[2];
            #pragma unroll
            for (int s = 0; s < 2; ++s)
                a1[s] = *(const bf16x8*)&lnb[mt * 16 + nlo][s * 32 + quad * 8];
            #pragma unroll
            for (int t1 = 0; t1 < 4; ++t1) {
                f32x4 c = {0.f, 0.f, 0.f, 0.f};
                c = __builtin_amdgcn_mfma_f32_16x16x32_bf16(a1[0], b1f[t1][0], c, 0, 0, 0);
                c = __builtin_amdgcn_mfma_f32_16x16x32_bf16(a1[1], b1f[t1][1], c, 0, 0, 0);
                #pragma unroll
                for (int r = 0; r < 4; ++r) {
                    float h = c[r] + b1v[t1];
                    h = 0.5f * h * (1.f + erff(h * 0.70710678f));
                    gb[mt * 16 + quad * 4 + r][(4 * w + t1) * 16 + nlo] = f2bf(h);
                }
            }
        }
        __syncthreads();

        #pragma unroll
        for (int mt = 0; mt < 2; ++mt) {
            f32x4 c2 = {0.f, 0.f, 0.f, 0.f};
            #pragma unroll
            for (int s2 = 0; s2 < 8; ++s2) {
                bf16x8 a2 = *(const bf16x8*)&gb[mt * 16 + nlo][s2 * 32 + quad * 8];
                c2 = __builtin_amdgcn_mfma_f32_16x16x32_bf16(a2, b2f[s2], c2, 0, 0, 0);
            }
            #pragma unroll
            for (int r = 0; r < 4; ++r) {
                const int node = base + mt * 16 + quad * 4 + r;
                const int cch  = w * 16 + nlo;
                float h2 = c2[r] + b2v;
                out[(size_t)node * C_CH + cch] =
                    lsv * h2 + x[(size_t)node * C_CH + cch];
            }
        }
        __syncthreads();
    }
}

extern "C" void kernel_launch(void* const* d_in, const int* in_sizes, int n_in,
                              void* d_out, int out_size, void* d_ws, size_t ws_size,
                              hipStream_t stream) {
    const float* x   = (const float*)d_in[0];
    const float* kb  = (const float*)d_in[1];
    // d_in[2] = fiber_kernel_basis (unused)
    const int*   ei  = (const int*)d_in[3];
    const float* kW  = (const float*)d_in[4];
    const float* cb  = (const float*)d_in[5];
    const float* gm  = (const float*)d_in[6];
    const float* bt  = (const float*)d_in[7];
    const float* W1  = (const float*)d_in[8];
    const float* b1  = (const float*)d_in[9];
    const float* W2  = (const float*)d_in[10];
    const float* b2  = (const float*)d_in[11];
    const float* ls  = (const float*)d_in[12];
    float* out = (float*)d_out;

    ushort_t* x1b = (ushort_t*)d_ws;   // [N, C] bf16 accumulator, 12.8 MB
    hipMemsetAsync(x1b, 0, (size_t)N_NODES * C_CH * sizeof(ushort_t), stream);

    edge_kernel<<<4096, 256, 0, stream>>>(x, kb, ei, kW, x1b);
    node_kernel<<<2048, 256, 0, stream>>>(x, x1b, cb, gm, bt, W1, b1, W2, b2, ls, out);
}